// Round 5
// baseline (335.095 us; speedup 1.0000x reference)
//
#include <hip/hip_runtime.h>
#include <hip/hip_bf16.h>
#include <stdint.h>

// ---------- types ----------
typedef __bf16  bf16x8 __attribute__((ext_vector_type(8)));
typedef short   s16x8  __attribute__((ext_vector_type(8)));
typedef short   s16x4  __attribute__((ext_vector_type(4)));
typedef int     i32x4  __attribute__((ext_vector_type(4)));
typedef float   f32x4  __attribute__((ext_vector_type(4)));

union Frag { s16x8 s; bf16x8 b; i32x4 i; };

static __device__ __forceinline__ short f2bf(float f) {
    union { float f; unsigned u; } v; v.f = f;
    unsigned r = (v.u + 0x7FFFu + ((v.u >> 16) & 1u)) >> 16;   // RNE
    return (short)r;
}
static __device__ __forceinline__ float fast_rcp(float x) { return __builtin_amdgcn_rcpf(x); }
static __device__ __forceinline__ float sigm(float x) { return fast_rcp(1.0f + __expf(-x)); }
static __device__ __forceinline__ float tanh_fast(float x) {
    float e = __expf(-2.0f * x);
    return (1.0f - e) * fast_rcp(1.0f + e);
}
static __device__ __forceinline__ f32x4 mfma16(bf16x8 a, bf16x8 b, f32x4 c) {
    return __builtin_amdgcn_mfma_f32_16x16x32_bf16(a, b, c, 0, 0, 0);
}

#define GLDS(gp, lp) __builtin_amdgcn_global_load_lds( \
    (const __attribute__((address_space(1))) void*)(gp), \
    (__attribute__((address_space(3))) void*)(lp), 16, 0, 0)

// raw barrier: LDS-ordering only — vm ops stay outstanding
#define BAR_LGKM() asm volatile("s_waitcnt lgkmcnt(0)\n\ts_barrier" ::: "memory")
#define BAR_ALL()  asm volatile("s_waitcnt vmcnt(0) lgkmcnt(0)\n\ts_barrier" ::: "memory")

// Constants
#define TT 128
#define BB 2048
#define HH 64
#define FF 128
#define AA 15
#define YR 32                 // y LDS ring slots
#define LOGITS_OFF 0
#define VF_OFF   3932160
#define HT_OFF   4194304
#define CT_OFF   4325376

// y_sw swizzled: per 16-row tile: 1024 bf16 = [kf(2)][lane(64)][8] (B-frag order)
// z_g: per (t,blk) tile: 1024 bf16 = [batch_row(16)][hcol(64)] — read directly
//      as head-B-frags: lane(q,c) loads cols 8q..8q+7 of batch c (16 B aligned).

// ============================ encoder ============================
__global__ __launch_bounds__(256) void enc_kernel(
    const float* __restrict__ x, const float* __restrict__ W1, const float* __restrict__ b1,
    const float* __restrict__ W2, const float* __restrict__ b2, short* __restrict__ y_sw)
{
    __shared__ short w1t[64][136];
    __shared__ short w2t[64][72];
    __shared__ short c1buf[4][16][72];
    __shared__ short ybuf[4][16][72];

    const int tid  = threadIdx.x;
    const int lane = tid & 63;
    const int w    = tid >> 6;
    const int c    = lane & 15;
    const int q    = lane >> 4;

    for (int i = tid; i < 128*64; i += 256) { int k = i >> 6, n = i & 63; w1t[n][k] = f2bf(W1[i]); }
    for (int i = tid; i < 64*64;  i += 256) { int k = i >> 6, n = i & 63; w2t[n][k] = f2bf(W2[i]); }

    float b1v[4], b2v[4];
#pragma unroll
    for (int ct = 0; ct < 4; ++ct) { b1v[ct] = b1[16*ct + c]; b2v[ct] = b2[16*ct + c]; }
    __syncthreads();

    const int wt = blockIdx.x*4 + w;     // one 16-row tile per wave
    const int r0 = wt * 16;
    Frag af[4];
#pragma unroll
    for (int kf = 0; kf < 4; ++kf) {
        const float* xp = x + (size_t)(r0 + c)*FF + 32*kf + 8*q;
        f32x4 x0 = *(const f32x4*)xp;
        f32x4 x1 = *(const f32x4*)(xp + 4);
#pragma unroll
        for (int jj = 0; jj < 4; ++jj) { af[kf].s[jj] = f2bf(x0[jj]); af[kf].s[4+jj] = f2bf(x1[jj]); }
    }
    f32x4 acc[4];
#pragma unroll
    for (int ct = 0; ct < 4; ++ct) acc[ct] = (f32x4){b1v[ct], b1v[ct], b1v[ct], b1v[ct]};
#pragma unroll
    for (int kf = 0; kf < 4; ++kf)
#pragma unroll
        for (int ct = 0; ct < 4; ++ct) {
            Frag bf; bf.s = *(const s16x8*)&w1t[16*ct + c][32*kf + 8*q];
            acc[ct] = mfma16(af[kf].b, bf.b, acc[ct]);
        }
#pragma unroll
    for (int ct = 0; ct < 4; ++ct)
#pragma unroll
        for (int i = 0; i < 4; ++i)
            c1buf[w][4*q + i][16*ct + c] = f2bf(tanh_fast(acc[ct][i]));
    Frag a2[2];
#pragma unroll
    for (int kf = 0; kf < 2; ++kf) a2[kf].s = *(const s16x8*)&c1buf[w][c][32*kf + 8*q];
    f32x4 acc2[4];
#pragma unroll
    for (int ct = 0; ct < 4; ++ct) acc2[ct] = (f32x4){b2v[ct], b2v[ct], b2v[ct], b2v[ct]};
#pragma unroll
    for (int kf = 0; kf < 2; ++kf)
#pragma unroll
        for (int ct = 0; ct < 4; ++ct) {
            Frag bf; bf.s = *(const s16x8*)&w2t[16*ct + c][32*kf + 8*q];
            acc2[ct] = mfma16(a2[kf].b, bf.b, acc2[ct]);
        }
#pragma unroll
    for (int ct = 0; ct < 4; ++ct)
#pragma unroll
        for (int i = 0; i < 4; ++i)
            ybuf[w][4*q + i][16*ct + c] = f2bf(tanh_fast(acc2[ct][i]));
#pragma unroll
    for (int kf = 0; kf < 2; ++kf) {
        s16x8 yv = *(const s16x8*)&ybuf[w][c][32*kf + 8*q];
        *(s16x8*)(y_sw + (size_t)wt*1024 + kf*512 + lane*8) = yv;
    }
}

// ============================ LSTM scan (minimal critical chain) ============================
// 128 blocks x 256 thr (4 waves). Transposed gates: A=weights(regs), B=state.
// Per-step barrier region contains ONLY: h-read (2xb128) -> mask -> 2-deep
// MFMA (C preloaded with bias+y@Wih from previous step) -> elementwise ->
// h-write + z-store. y[t+1]/done[t+1]/gy[t+1] prepared off-chain each step.
__global__ __launch_bounds__(256, 1) void scan_kernel(
    const short* __restrict__ y_sw, const float* __restrict__ done,
    const float* __restrict__ h0, const float* __restrict__ c0,
    const float* __restrict__ Wih, const float* __restrict__ bih,
    const float* __restrict__ Whh, const float* __restrict__ bhh,
    short* __restrict__ z_g, float* __restrict__ hT_out, float* __restrict__ cT_out)
{
    __shared__ short ybig[YR][1024];      // 64 KB  y ring (B-frag order)
    __shared__ short hbuf[2][16][72];     // 4.6 KB double-buffered h (bf16)
    __shared__ float dbuf[TT][16];        // 8 KB   done, all steps

    const int tid  = threadIdx.x;
    const int lane = tid & 63;
    const int w    = tid >> 6;
    const int c    = lane & 15;
    const int q    = lane >> 4;
    const int blk  = blockIdx.x;
    const int b0   = blk * 16;

    // ---- A-frag weights: wfr[a][kf] = W[64a+16w+c][32kf+8q+j] (kf<2: Wih, else Whh)
    Frag  wfr[4][4];
    f32x4 biasv[4];
#pragma unroll
    for (int a = 0; a < 4; ++a) {
        const int gc = 64*a + 16*w + c;
#pragma unroll
        for (int kf = 0; kf < 4; ++kf) {
            const float* wp = (kf < 2) ? (Wih + (size_t)gc*HH + 32*kf + 8*q)
                                       : (Whh + (size_t)gc*HH + 32*(kf-2) + 8*q);
            f32x4 w0 = *(const f32x4*)wp;
            f32x4 w1 = *(const f32x4*)(wp + 4);
#pragma unroll
            for (int jj = 0; jj < 4; ++jj) { wfr[a][kf].s[jj] = f2bf(w0[jj]); wfr[a][kf].s[4+jj] = f2bf(w1[jj]); }
        }
        const int bcol = 64*a + 16*w + 4*q;
        biasv[a] = *(const f32x4*)(bih + bcol);
        f32x4 bx = *(const f32x4*)(bhh + bcol);
#pragma unroll
        for (int jj = 0; jj < 4; ++jj) biasv[a][jj] += bx[jj];
    }
    // ---- c state: (brow c, hcols 16w+4q+i)
    f32x4 cst = *(const f32x4*)(c0 + (size_t)(b0 + c)*HH + 16*w + 4*q);
    // ---- h0 -> hbuf[1] (step 0 reads buffer 1)
    {
        int r = tid & 15, c4 = (tid >> 4) * 4;
        f32x4 hvv = *(const f32x4*)(h0 + (size_t)(b0 + r)*HH + c4);
        s16x4 hp;
#pragma unroll
        for (int ii = 0; ii < 4; ++ii) hp[ii] = f2bf(hvv[ii]);
        *(s16x4*)&hbuf[1][r][c4] = hp;
    }
    // ---- done -> dbuf
#pragma unroll
    for (int i = 0; i < 2; ++i) {
        int j = w*2 + i;
        const float* gp = done + (size_t)(16*j + (lane >> 2))*BB + b0 + 4*(lane & 3);
        GLDS(gp, &dbuf[16*j][0]);
    }
    // ---- y ring prologue: slots 0..30
    for (int s = w; s < 31; s += 4)
#pragma unroll
        for (int half = 0; half < 2; ++half) {
            const short* gp = y_sw + ((size_t)s*128 + blk)*1024 + half*512 + lane*8;
            GLDS(gp, &ybig[s][half*512]);
        }
    BAR_ALL();

    // ---- prologue: dme, gy for t=0
    float dme = dbuf[0][c];
    f32x4 g2[4];
    {
        Frag y0, y1;
        y0.s = *(const s16x8*)&ybig[0][lane*8];
        y1.s = *(const s16x8*)&ybig[0][512 + lane*8];
#pragma unroll
        for (int a = 0; a < 4; ++a) {
            g2[a] = mfma16(wfr[a][0].b, y0.b, biasv[a]);
            g2[a] = mfma16(wfr[a][1].b, y1.b, g2[a]);
        }
    }
    f32x4 hv;

    for (int t = 0; t < TT; ++t) {
        const int rb = (t + 1) & 1, wb = t & 1;
        // ---- critical chain: h read -> mask -> 2-deep MFMA -> elementwise
        Frag hf0, hf1;
        hf0.s = *(const s16x8*)&hbuf[rb][c][8*q];
        hf1.s = *(const s16x8*)&hbuf[rb][c][32 + 8*q];
        const int msk = (dme != 0.0f) ? 0 : -1;
        Frag zm0, zm1;
#pragma unroll
        for (int k = 0; k < 4; ++k) { zm0.i[k] = hf0.i[k] & msk; zm1.i[k] = hf1.i[k] & msk; }
        f32x4 acc[4];
#pragma unroll
        for (int a = 0; a < 4; ++a) {
            acc[a] = mfma16(wfr[a][2].b, zm0.b, g2[a]);
            acc[a] = mfma16(wfr[a][3].b, zm1.b, acc[a]);
        }
#pragma unroll
        for (int i = 0; i < 4; ++i) {
            float cm = (dme != 0.0f) ? 0.0f : cst[i];
            float cn = sigm(acc[1][i])*cm + sigm(acc[0][i])*tanh_fast(acc[2][i]);
            cst[i] = cn;
            hv[i]  = sigm(acc[3][i])*tanh_fast(cn);
        }
        s16x4 hp;
#pragma unroll
        for (int ii = 0; ii < 4; ++ii) hp[ii] = f2bf(hv[ii]);
        *(s16x4*)&hbuf[wb][c][16*w + 4*q] = hp;                        // h exchange
        *(s16x4*)(z_g + ((size_t)t*128 + blk)*1024 + c*64 + 16*w + 4*q) = hp;  // z stream
        // ---- off-chain tail: prepare t+1
        if (t < TT-1) {
            Frag yn0, yn1;
            yn0.s = *(const s16x8*)&ybig[(t+1) & (YR-1)][lane*8];
            yn1.s = *(const s16x8*)&ybig[(t+1) & (YR-1)][512 + lane*8];
            dme = dbuf[t+1][c];
#pragma unroll
            for (int a = 0; a < 4; ++a) {
                g2[a] = mfma16(wfr[a][0].b, yn0.b, biasv[a]);
                g2[a] = mfma16(wfr[a][1].b, yn1.b, g2[a]);
            }
        }
        if (w == (t & 3) && t <= TT-32) {      // stage y[t+31]
            const int ds = (t + 31) & (YR-1);
#pragma unroll
            for (int half = 0; half < 2; ++half) {
                const short* gp = y_sw + ((size_t)(t+31)*128 + blk)*1024 + half*512 + lane*8;
                GLDS(gp, &ybig[ds][half*512]);
            }
        }
        BAR_LGKM();
    }
    // ---- epilogue: hT, cT (z[127] already streamed)
    *(f32x4*)(hT_out + (size_t)(b0 + c)*HH + 16*w + 4*q) = hv;
    *(f32x4*)(cT_out + (size_t)(b0 + c)*HH + 16*w + 4*q) = cst;
}

// ============================ heads ============================
// out^T = Whead^T @ z^T per 16-row tile; B-frags load straight from z_g layout.
__global__ __launch_bounds__(256) void heads_kernel(
    const short* __restrict__ z_g, const float* __restrict__ Wa, const float* __restrict__ ba,
    const float* __restrict__ Wc, const float* __restrict__ bc,
    float* __restrict__ out_logits, float* __restrict__ out_vf)
{
    const int tid  = threadIdx.x;
    const int lane = tid & 63;
    const int w    = tid >> 6;
    const int c    = lane & 15;
    const int q    = lane >> 4;

    // A-frags: lane(q,c): A[m=out c][k=8q+j] = W[k][c]
    Frag hwf[2];
#pragma unroll
    for (int kf = 0; kf < 2; ++kf)
#pragma unroll
        for (int jj = 0; jj < 8; ++jj) {
            int k = 32*kf + 8*q + jj;
            hwf[kf].s[jj] = f2bf((c < 15) ? Wa[k*AA + c] : Wc[k]);
        }
    const float bv = (c < 15) ? ba[c] : bc[0];

    for (int s = 0; s < 4; ++s) {
        const int wt = s*4096 + blockIdx.x*4 + w;   // tile id (t*128+blk)
        const short* zt = z_g + (size_t)wt*1024;
        Frag b0, b1;
        b0.s = *(const s16x8*)(zt + c*64 + 8*q);        // cols 8q..8q+7, batch c
        b1.s = *(const s16x8*)(zt + c*64 + 32 + 8*q);   // cols 32+8q..
        f32x4 acc = (f32x4){bv, bv, bv, bv};
        acc = mfma16(hwf[0].b, b0.b, acc);
        acc = mfma16(hwf[1].b, b1.b, acc);
        // lane(q,c): out[batch row wt*16+c][head-outs 4q..4q+3]
        const size_t row = (size_t)wt*16 + c;
        float* lp = out_logits + row*AA + 4*q;
        if (q < 3) {
            lp[0]=acc[0]; lp[1]=acc[1]; lp[2]=acc[2]; lp[3]=acc[3];
        } else {
            lp[0]=acc[0]; lp[1]=acc[1]; lp[2]=acc[2];
            out_vf[row] = acc[3];
        }
    }
}

// ============================ launch ============================
extern "C" void kernel_launch(void* const* d_in, const int* in_sizes, int n_in,
                              void* d_out, int out_size, void* d_ws, size_t ws_size,
                              hipStream_t stream) {
    const float* x    = (const float*)d_in[0];
    const float* done = (const float*)d_in[1];
    const float* h0   = (const float*)d_in[2];
    const float* c0   = (const float*)d_in[3];
    const float* W1   = (const float*)d_in[4];
    const float* b1   = (const float*)d_in[5];
    const float* W2   = (const float*)d_in[6];
    const float* b2   = (const float*)d_in[7];
    const float* Wih  = (const float*)d_in[8];
    const float* bih  = (const float*)d_in[9];
    const float* Whh  = (const float*)d_in[10];
    const float* bhh  = (const float*)d_in[11];
    const float* Wa   = (const float*)d_in[12];
    const float* ba   = (const float*)d_in[13];
    const float* Wc   = (const float*)d_in[14];
    const float* bc   = (const float*)d_in[15];
    float* out = (float*)d_out;

    short* y_sw = (short*)d_ws;           // 32 MiB swizzled encoder output
    short* z_g  = y_sw + 16777216;        // 32 MiB z stream ([tile][row][col])

    enc_kernel<<<4096, 256, 0, stream>>>(x, W1, b1, W2, b2, y_sw);
    scan_kernel<<<128, 256, 0, stream>>>(y_sw, done, h0, c0, Wih, bih, Whh, bhh,
                                         z_g, out + HT_OFF, out + CT_OFF);
    heads_kernel<<<1024, 256, 0, stream>>>(z_g, Wa, ba, Wc, bc,
                                           out + LOGITS_OFF, out + VF_OFF);
}